// Round 1
// baseline (875.133 us; speedup 1.0000x reference)
//
#include <hip/hip_runtime.h>

#define DEV __device__ __forceinline__

using bf16x8 = __attribute__((ext_vector_type(8))) __bf16;
using f32x4  = __attribute__((ext_vector_type(4))) float;

namespace {
constexpr int SPAT = 50176;    // 16*56*56
constexpr int TOK  = 100352;   // 2*SPAT
constexpr int NTOK = 392;      // tokens per window
constexpr int NTP  = 416;      // padded token count (26*16)
}

DEV float bf2f(short s){ unsigned u = ((unsigned)(unsigned short)s) << 16; float f; __builtin_memcpy(&f, &u, 4); return f; }
DEV short f2bf(float f){ unsigned u; __builtin_memcpy(&u, &f, 4); u = (u + 0x7fffu + ((u >> 16) & 1u)) >> 16; return (short)u; }
DEV f32x4 mfma16(bf16x8 a, bf16x8 b, f32x4 c){ return __builtin_amdgcn_mfma_f32_16x16x32_bf16(a, b, c, 0, 0, 0); }

// Swin region label for mask: window wi (nd,nh,nw), token n (wd,wh,ww)
DEV int swin_label(int wi, int n){
  int nd = (wi >> 6) & 1, nh = (wi >> 3) & 7, nw = wi & 7;
  int wd = n / 49, wh = (n / 7) % 7, ww = n % 7;
  int d = nd * 8 + wd, h = nh * 7 + wh, w = nw * 7 + ww;
  int ld = d < 8 ? 0 : (d < 12 ? 1 : 2);
  int lh = h < 49 ? 0 : (h < 53 ? 1 : 2);
  int lw = w < 49 ? 0 : (w < 53 ? 1 : 2);
  return ld * 9 + lh * 3 + lw;
}

// ---------------- K0: convert weights fp32 -> bf16 ----------------
__global__ __launch_bounds__(256) void k_convert(const float* __restrict__ qkvw, const float* __restrict__ projw,
                                                 const float* __restrict__ fc1w, const float* __restrict__ fc2w,
                                                 short* __restrict__ wq, short* __restrict__ wp,
                                                 short* __restrict__ w1, short* __restrict__ w2){
  int i = blockIdx.x * 256 + threadIdx.x;
  if (i < 49152)        wq[i]          = f2bf(qkvw[i]);
  else if (i < 65536)   wp[i - 49152]  = f2bf(projw[i - 49152]);
  else if (i < 131072)  w1[i - 65536]  = f2bf(fc1w[i - 65536]);
  else if (i < 196608)  w2[i - 131072] = f2bf(fc2w[i - 131072]);
}

// ---------------- K1: LN1 + roll + window partition -> win bf16 [TOK][128] ----------------
__global__ __launch_bounds__(256) void k_ln1(const float* __restrict__ x, const float* __restrict__ w,
                                             const float* __restrict__ b, short* __restrict__ win){
  int m = blockIdx.x * 256 + threadIdx.x;            // < TOK
  int bb = m / SPAT, p = m % SPAT;
  const float* xp = x + (size_t)bb * 128 * SPAT + p;
  float s = 0.f, s2 = 0.f;
  for (int c = 0; c < 128; c++){ float v = xp[(size_t)c * SPAT]; s += v; s2 += v * v; }
  float mu = s * (1.f / 128.f);
  float var = s2 * (1.f / 128.f) - mu * mu;
  float rs = rsqrtf(var + 1e-5f);
  int d = p / 3136, hw = p % 3136, h = hw / 56, wq = hw % 56;
  int dr = (d + 12) & 15, hr = (h + 53) % 56, wr = (wq + 53) % 56;
  int nd = dr >> 3, wd = dr & 7, nh = hr / 7, wh = hr % 7, nw = wr / 7, ww = wr % 7;
  int wi = ((bb * 2 + nd) << 6) + (nh << 3) + nw;
  int n = (wd * 7 + wh) * 7 + ww;
  short* dst = win + (size_t)(wi * NTOK + n) * 128;
  for (int c = 0; c < 128; c++){
    float v = (xp[(size_t)c * SPAT] - mu) * rs * w[c] + b[c];
    dst[c] = f2bf(v);
  }
}

// ---------------- K2: relative position bias table [4][392][392] ----------------
__global__ __launch_bounds__(256) void k_bias(const float* __restrict__ rpb, float* __restrict__ bias){
  int t = blockIdx.x * 256 + threadIdx.x;
  if (t >= NTOK * NTOK) return;
  int i = t / NTOK, j = t % NTOK;
  int wdi = i / 49, whi = (i / 7) % 7, wwi = i % 7;
  int wdj = j / 49, whj = (j / 7) % 7, wwj = j % 7;
  int idx = (wdi - wdj + 7) * 169 + (whi - whj + 6) * 13 + (wwi - wwj + 6);
  for (int h = 0; h < 4; h++)
    bias[((size_t)h * NTOK + i) * NTOK + j] = rpb[idx * 4 + h];
}

// ---------------- K3: QKV GEMM + scatter into Q/K/Vt ----------------
__global__ __launch_bounds__(256) void k_qkv(const short* __restrict__ win, const short* __restrict__ wq,
                                             const float* __restrict__ qb, short* __restrict__ Q,
                                             short* __restrict__ K, short* __restrict__ Vt){
  int lane = threadIdx.x & 63, wv = threadIdx.x >> 6;
  int m0 = (blockIdx.x % 1568) * 64 + wv * 16;
  int c0 = (blockIdx.x / 1568) * 64;
  int cc = lane & 15, g = lane >> 4;
  f32x4 acc[4] = {};
  bf16x8 af[4];
  for (int k = 0; k < 4; k++)
    af[k] = *reinterpret_cast<const bf16x8*>(win + (size_t)(m0 + cc) * 128 + k * 32 + g * 8);
  for (int k = 0; k < 4; k++){
    for (int ct = 0; ct < 4; ct++){
      bf16x8 bf = *reinterpret_cast<const bf16x8*>(wq + (size_t)(c0 + ct * 16 + cc) * 128 + k * 32 + g * 8);
      acc[ct] = mfma16(af[k], bf, acc[ct]);
    }
  }
  for (int ct = 0; ct < 4; ct++){
    int o = c0 + ct * 16 + cc;
    int sec = o >> 7, oo = o & 127, head = oo >> 5, hd = oo & 31;
    float bv = qb[o];
    for (int r = 0; r < 4; r++){
      int m = m0 + g * 4 + r;
      float v = acc[ct][r] + bv;
      int wi = m / NTOK, n = m % NTOK;
      if (sec == 0){
        v *= 0.17677669529663687f;
        Q[((size_t)(wi * 4 + head) * NTP + n) * 32 + hd] = f2bf(v);
      } else if (sec == 1){
        K[((size_t)(wi * 4 + head) * NTP + n) * 32 + hd] = f2bf(v);
      } else {
        Vt[((size_t)(wi * 4 + head) * 32 + hd) * NTP + n] = f2bf(v);
      }
    }
  }
}

// ---------------- K4: windowed flash attention ----------------
__global__ __launch_bounds__(256) void k_attn(const short* __restrict__ Q, const short* __restrict__ K,
                                              const short* __restrict__ Vt, const float* __restrict__ bias,
                                              short* __restrict__ O){
  __shared__ short plds[4][16][56];   // per-wave P tile, 112B row stride (16B-aligned, conflict-light)
  int lane = threadIdx.x & 63, wv = threadIdx.x >> 6;
  int wg = blockIdx.x * 4 + wv;
  int qt = wg % 25; int t2 = wg / 25; int head = t2 & 3; int wi = t2 >> 2;
  int q0 = qt * 16;
  const short* Qb = Q + (size_t)(wi * 4 + head) * NTP * 32;
  const short* Kb = K + (size_t)(wi * 4 + head) * NTP * 32;
  const short* Vb = Vt + (size_t)(wi * 4 + head) * 32 * NTP;
  const float* Bb = bias + (size_t)head * NTOK * NTOK;
  int cc = lane & 15, g = lane >> 4;
  bf16x8 qf = *reinterpret_cast<const bf16x8*>(Qb + (q0 + cc) * 32 + g * 8);
  int irow[4], lbli[4];
  for (int r = 0; r < 4; r++){
    int i = q0 + g * 4 + r; irow[r] = i;
    lbli[r] = swin_label(wi, i < NTOK ? i : NTOK - 1);
  }
  float mrun[4], lrun[4];
  f32x4 acc0 = {}, acc1 = {};
  for (int r = 0; r < 4; r++){ mrun[r] = -1e30f; lrun[r] = 0.f; }
  for (int jt = 0; jt < 13; jt++){
    int j0 = jt * 32;
    int jg0 = j0 + cc, jg1 = j0 + 16 + cc;
    bf16x8 kf0 = *reinterpret_cast<const bf16x8*>(Kb + jg0 * 32 + g * 8);
    bf16x8 kf1 = *reinterpret_cast<const bf16x8*>(Kb + jg1 * 32 + g * 8);
    f32x4 z = {};
    f32x4 s0 = mfma16(qf, kf0, z);
    f32x4 s1 = mfma16(qf, kf1, z);
    int lblj0 = jg0 < NTOK ? swin_label(wi, jg0) : -1;
    int lblj1 = jg1 < NTOK ? swin_label(wi, jg1) : -1;
    for (int r = 0; r < 4; r++){
      int ii = irow[r] < NTOK ? irow[r] : NTOK - 1;
      float v0 = (jg0 < NTOK) ? s0[r] + Bb[(size_t)ii * NTOK + jg0] + (lblj0 != lbli[r] ? -100.f : 0.f) : -1e30f;
      float v1 = (jg1 < NTOK) ? s1[r] + Bb[(size_t)ii * NTOK + jg1] + (lblj1 != lbli[r] ? -100.f : 0.f) : -1e30f;
      float vm = fmaxf(v0, v1);
      #pragma unroll
      for (int off = 1; off < 16; off <<= 1) vm = fmaxf(vm, __shfl_xor(vm, off));
      float mn = fmaxf(mrun[r], vm);
      float al = __expf(mrun[r] - mn);
      float p0 = __expf(v0 - mn), p1 = __expf(v1 - mn);
      float ps = p0 + p1;
      #pragma unroll
      for (int off = 1; off < 16; off <<= 1) ps += __shfl_xor(ps, off);
      lrun[r] = lrun[r] * al + ps;
      mrun[r] = mn;
      acc0[r] *= al; acc1[r] *= al;
      int rr = g * 4 + r;
      plds[wv][rr][cc]      = f2bf(p0);
      plds[wv][rr][cc + 16] = f2bf(p1);
    }
    asm volatile("s_waitcnt lgkmcnt(0)" ::: "memory");
    bf16x8 pf  = *reinterpret_cast<const bf16x8*>(&plds[wv][cc][g * 8]);
    bf16x8 vf0 = *reinterpret_cast<const bf16x8*>(Vb + cc * NTP + j0 + g * 8);
    bf16x8 vf1 = *reinterpret_cast<const bf16x8*>(Vb + (cc + 16) * NTP + j0 + g * 8);
    acc0 = mfma16(pf, vf0, acc0);
    acc1 = mfma16(pf, vf1, acc1);
  }
  for (int r = 0; r < 4; r++){
    int i = irow[r];
    if (i < NTOK){
      float inv = 1.f / lrun[r];
      size_t o = (size_t)(wi * NTOK + i) * 128 + head * 32;
      O[o + cc]      = f2bf(acc0[r] * inv);
      O[o + 16 + cc] = f2bf(acc1[r] * inv);
    }
  }
}

// ---------------- K5: proj GEMM -> projwin bf16 [TOK][128] ----------------
__global__ __launch_bounds__(256) void k_proj(const short* __restrict__ A, const short* __restrict__ Bw,
                                              const float* __restrict__ pb, short* __restrict__ Cout){
  int lane = threadIdx.x & 63, wv = threadIdx.x >> 6;
  int m0 = (blockIdx.x % 1568) * 64 + wv * 16;
  int c0 = (blockIdx.x / 1568) * 64;
  int cc = lane & 15, g = lane >> 4;
  f32x4 acc[4] = {};
  bf16x8 af[4];
  for (int k = 0; k < 4; k++)
    af[k] = *reinterpret_cast<const bf16x8*>(A + (size_t)(m0 + cc) * 128 + k * 32 + g * 8);
  for (int k = 0; k < 4; k++){
    for (int ct = 0; ct < 4; ct++){
      bf16x8 bf = *reinterpret_cast<const bf16x8*>(Bw + (size_t)(c0 + ct * 16 + cc) * 128 + k * 32 + g * 8);
      acc[ct] = mfma16(af[k], bf, acc[ct]);
    }
  }
  for (int ct = 0; ct < 4; ct++){
    int o = c0 + ct * 16 + cc;
    float bv = pb[o];
    for (int r = 0; r < 4; r++){
      int m = m0 + g * 4 + r;
      Cout[(size_t)m * 128 + o] = f2bf(acc[ct][r] + bv);
    }
  }
}

// ---------------- K6: residual1 + LN2 -> d_out (x1) + h2n bf16 [TOK][128] ----------------
__global__ __launch_bounds__(256) void k_res1(const float* __restrict__ x, const short* __restrict__ pwin,
                                              const float* __restrict__ w2, const float* __restrict__ b2,
                                              float* __restrict__ out, short* __restrict__ h2n){
  int m = blockIdx.x * 256 + threadIdx.x;
  int bb = m / SPAT, p = m % SPAT;
  int d = p / 3136, hw = p % 3136, h = hw / 56, wq = hw % 56;
  int dr = (d + 12) & 15, hr = (h + 53) % 56, wr = (wq + 53) % 56;
  int nd = dr >> 3, wd = dr & 7, nh = hr / 7, wh = hr % 7, nw = wr / 7, ww = wr % 7;
  int wi = ((bb * 2 + nd) << 6) + (nh << 3) + nw;
  int n = (wd * 7 + wh) * 7 + ww;
  const float* xp = x + (size_t)bb * 128 * SPAT + p;
  const short* pw = pwin + (size_t)(wi * NTOK + n) * 128;
  float s = 0.f, s2 = 0.f;
  for (int c = 0; c < 128; c++){
    float v = xp[(size_t)c * SPAT] + bf2f(pw[c]);
    s += v; s2 += v * v;
  }
  float mu = s * (1.f / 128.f);
  float var = s2 * (1.f / 128.f) - mu * mu;
  float rs = rsqrtf(var + 1e-5f);
  float* op = out + (size_t)bb * 128 * SPAT + p;
  short* hp = h2n + (size_t)m * 128;
  for (int c = 0; c < 128; c++){
    float v = xp[(size_t)c * SPAT] + bf2f(pw[c]);
    op[(size_t)c * SPAT] = v;
    hp[c] = f2bf((v - mu) * rs * w2[c] + b2[c]);
  }
}

// ---------------- K7: fused FFN (fc1 + gelu + fc2) accumulated into d_out ----------------
__global__ __launch_bounds__(256) void k_ffn(const short* __restrict__ h2n, const short* __restrict__ w1,
                                             const float* __restrict__ b1, const short* __restrict__ w2,
                                             const float* __restrict__ b2, float* __restrict__ out){
  __shared__ short smid[64 * 520];   // [64 tokens][512 mid], 1040B row stride
  __shared__ float sout[64 * 129];   // [64 tokens][128 out], +1 pad
  int lane = threadIdx.x & 63, wv = threadIdx.x >> 6;
  int t0 = blockIdx.x * 64;
  int cc = lane & 15, g = lane >> 4;
  // stage 1: mid = gelu(h2n @ fc1^T + b1)
  bf16x8 af[4];
  for (int k = 0; k < 4; k++)
    af[k] = *reinterpret_cast<const bf16x8*>(h2n + (size_t)(t0 + wv * 16 + cc) * 128 + k * 32 + g * 8);
  for (int ct = 0; ct < 32; ct++){
    f32x4 acc = {};
    for (int k = 0; k < 4; k++){
      bf16x8 bf = *reinterpret_cast<const bf16x8*>(w1 + (size_t)(ct * 16 + cc) * 128 + k * 32 + g * 8);
      acc = mfma16(af[k], bf, acc);
    }
    int o = ct * 16 + cc;
    float bv = b1[o];
    for (int r = 0; r < 4; r++){
      int lr = wv * 16 + g * 4 + r;
      float v = acc[r] + bv;
      float ge = 0.5f * v * (1.f + tanhf(0.7978845608028654f * (v + 0.044715f * v * v * v)));
      smid[lr * 520 + o] = f2bf(ge);
    }
  }
  __syncthreads();
  // stage 2: out = mid @ fc2^T + b2
  f32x4 acc2[8] = {};
  for (int ks = 0; ks < 16; ks++){
    bf16x8 a = *reinterpret_cast<const bf16x8*>(&smid[(wv * 16 + cc) * 520 + ks * 32 + g * 8]);
    for (int ct = 0; ct < 8; ct++){
      bf16x8 bf = *reinterpret_cast<const bf16x8*>(w2 + (size_t)(ct * 16 + cc) * 512 + ks * 32 + g * 8);
      acc2[ct] = mfma16(a, bf, acc2[ct]);
    }
  }
  for (int ct = 0; ct < 8; ct++){
    int o = ct * 16 + cc;
    float bv = b2[o];
    for (int r = 0; r < 4; r++){
      int lr = wv * 16 + g * 4 + r;
      sout[lr * 129 + o] = acc2[ct][r] + bv;
    }
  }
  __syncthreads();
  // transposed, coalesced RMW into channel-major output
  int bb = t0 / SPAT, p0 = t0 % SPAT;
  int poff = threadIdx.x & 63;
  int obase = threadIdx.x >> 6;
  float* op = out + (size_t)bb * 128 * SPAT + p0 + poff;
  for (int oi = 0; oi < 32; oi++){
    int o = obase + oi * 4;
    op[(size_t)o * SPAT] += sout[poff * 129 + o];
  }
}

extern "C" void kernel_launch(void* const* d_in, const int* in_sizes, int n_in,
                              void* d_out, int out_size, void* d_ws, size_t ws_size,
                              hipStream_t stream){
  const float* x     = (const float*)d_in[0];
  const float* n1w   = (const float*)d_in[1];
  const float* n1b   = (const float*)d_in[2];
  const float* qkvw  = (const float*)d_in[3];
  const float* qkvb  = (const float*)d_in[4];
  const float* rpb   = (const float*)d_in[5];
  const float* projw = (const float*)d_in[6];
  const float* projb = (const float*)d_in[7];
  const float* n2w   = (const float*)d_in[8];
  const float* n2b   = (const float*)d_in[9];
  const float* fc1w  = (const float*)d_in[10];
  const float* fc1b  = (const float*)d_in[11];
  const float* fc2w  = (const float*)d_in[12];
  const float* fc2b  = (const float*)d_in[13];
  float* out = (float*)d_out;

  char* ws = (char*)d_ws;
  size_t off = 0;
  auto alloc = [&](size_t bytes) -> void* {
    void* p = ws + off;
    off += (bytes + 255) & ~(size_t)255;
    return p;
  };
  short* win  = (short*)alloc((size_t)TOK * 128 * 2);
  short* Obuf = (short*)alloc((size_t)TOK * 128 * 2);
  short* pwin = (short*)alloc((size_t)TOK * 128 * 2);
  short* h2n  = (short*)alloc((size_t)TOK * 128 * 2);
  short* Qb   = (short*)alloc((size_t)1024 * NTP * 32 * 2);
  short* Kb   = (short*)alloc((size_t)1024 * NTP * 32 * 2);
  short* Vtb  = (short*)alloc((size_t)1024 * NTP * 32 * 2);
  float* bias = (float*)alloc((size_t)4 * NTOK * NTOK * 4);
  short* wq   = (short*)alloc(49152 * 2);
  short* wp   = (short*)alloc(16384 * 2);
  short* w1   = (short*)alloc(65536 * 2);
  short* w2   = (short*)alloc(65536 * 2);

  k_convert<<<768, 256, 0, stream>>>(qkvw, projw, fc1w, fc2w, wq, wp, w1, w2);
  k_ln1<<<TOK / 256, 256, 0, stream>>>(x, n1w, n1b, win);
  k_bias<<<(NTOK * NTOK + 255) / 256, 256, 0, stream>>>(rpb, bias);
  k_qkv<<<1568 * 6, 256, 0, stream>>>(win, wq, qkvb, Qb, Kb, Vtb);
  k_attn<<<6400, 256, 0, stream>>>(Qb, Kb, Vtb, bias, Obuf);
  k_proj<<<1568 * 2, 256, 0, stream>>>(Obuf, wp, projb, pwin);
  k_res1<<<TOK / 256, 256, 0, stream>>>(x, pwin, n2w, n2b, out, h2n);
  k_ffn<<<TOK / 64, 256, 0, stream>>>(h2n, w1, fc1b, w2, fc2b, out);
}

// Round 5
// 814.444 us; speedup vs baseline: 1.0745x; 1.0745x over previous
//
#include <hip/hip_runtime.h>

#define DEV __device__ __forceinline__

using bf16x8 = __attribute__((ext_vector_type(8))) __bf16;
using f32x4  = __attribute__((ext_vector_type(4))) float;

namespace {
constexpr int SPAT = 50176;    // 16*56*56
constexpr int TOK  = 100352;   // 2*SPAT
constexpr int NTOK = 392;      // tokens per window
constexpr int NTP  = 416;      // padded token count (26*16)
}

DEV float bf2f(short s){ unsigned u = ((unsigned)(unsigned short)s) << 16; float f; __builtin_memcpy(&f, &u, 4); return f; }
DEV short f2bf(float f){ unsigned u; __builtin_memcpy(&u, &f, 4); u = (u + 0x7fffu + ((u >> 16) & 1u)) >> 16; return (short)u; }
DEV f32x4 mfma16(bf16x8 a, bf16x8 b, f32x4 c){ return __builtin_amdgcn_mfma_f32_16x16x32_bf16(a, b, c, 0, 0, 0); }

// Swin region label for mask: window wi (nd,nh,nw), token n (wd,wh,ww)
DEV int swin_label(int wi, int n){
  int nd = (wi >> 6) & 1, nh = (wi >> 3) & 7, nw = wi & 7;
  int wd = n / 49, wh = (n / 7) % 7, ww = n % 7;
  int d = nd * 8 + wd, h = nh * 7 + wh, w = nw * 7 + ww;
  int ld = d < 8 ? 0 : (d < 12 ? 1 : 2);
  int lh = h < 49 ? 0 : (h < 53 ? 1 : 2);
  int lw = w < 49 ? 0 : (w < 53 ? 1 : 2);
  return ld * 9 + lh * 3 + lw;
}

// ---------------- K0: convert weights fp32 -> bf16 ----------------
__global__ __launch_bounds__(256) void k_convert(const float* __restrict__ qkvw, const float* __restrict__ projw,
                                                 const float* __restrict__ fc1w, const float* __restrict__ fc2w,
                                                 short* __restrict__ wq, short* __restrict__ wp,
                                                 short* __restrict__ w1, short* __restrict__ w2){
  int i = blockIdx.x * 256 + threadIdx.x;
  if (i < 49152)        wq[i]          = f2bf(qkvw[i]);
  else if (i < 65536)   wp[i - 49152]  = f2bf(projw[i - 49152]);
  else if (i < 131072)  w1[i - 65536]  = f2bf(fc1w[i - 65536]);
  else if (i < 196608)  w2[i - 131072] = f2bf(fc2w[i - 131072]);
}

// ---------------- K1: LN1 + roll + window partition -> win bf16 [TOK][128] ----------------
__global__ __launch_bounds__(256) void k_ln1(const float* __restrict__ x, const float* __restrict__ w,
                                             const float* __restrict__ b, short* __restrict__ win){
  int m = blockIdx.x * 256 + threadIdx.x;            // < TOK
  int bb = m / SPAT, p = m % SPAT;
  const float* xp = x + (size_t)bb * 128 * SPAT + p;
  float s = 0.f, s2 = 0.f;
  for (int c = 0; c < 128; c++){ float v = xp[(size_t)c * SPAT]; s += v; s2 += v * v; }
  float mu = s * (1.f / 128.f);
  float var = s2 * (1.f / 128.f) - mu * mu;
  float rs = rsqrtf(var + 1e-5f);
  int d = p / 3136, hw = p % 3136, h = hw / 56, wq = hw % 56;
  int dr = (d + 12) & 15, hr = (h + 53) % 56, wr = (wq + 53) % 56;
  int nd = dr >> 3, wd = dr & 7, nh = hr / 7, wh = hr % 7, nw = wr / 7, ww = wr % 7;
  int wi = ((bb * 2 + nd) << 6) + (nh << 3) + nw;
  int n = (wd * 7 + wh) * 7 + ww;
  short* dst = win + (size_t)(wi * NTOK + n) * 128;
  for (int c = 0; c < 128; c++){
    float v = (xp[(size_t)c * SPAT] - mu) * rs * w[c] + b[c];
    dst[c] = f2bf(v);
  }
}

// ---------------- K2: relative position bias table [4][392][392] ----------------
__global__ __launch_bounds__(256) void k_bias(const float* __restrict__ rpb, float* __restrict__ bias){
  int t = blockIdx.x * 256 + threadIdx.x;
  if (t >= NTOK * NTOK) return;
  int i = t / NTOK, j = t % NTOK;
  int wdi = i / 49, whi = (i / 7) % 7, wwi = i % 7;
  int wdj = j / 49, whj = (j / 7) % 7, wwj = j % 7;
  int idx = (wdi - wdj + 7) * 169 + (whi - whj + 6) * 13 + (wwi - wwj + 6);
  for (int h = 0; h < 4; h++)
    bias[((size_t)h * NTOK + i) * NTOK + j] = rpb[idx * 4 + h];
}

// ---------------- K3: QKV GEMM + scatter into Q/K/Vt ----------------
__global__ __launch_bounds__(256) void k_qkv(const short* __restrict__ win, const short* __restrict__ wq,
                                             const float* __restrict__ qb, short* __restrict__ Q,
                                             short* __restrict__ K, short* __restrict__ Vt){
  int lane = threadIdx.x & 63, wv = threadIdx.x >> 6;
  int m0 = (blockIdx.x % 1568) * 64 + wv * 16;
  int c0 = (blockIdx.x / 1568) * 64;
  int cc = lane & 15, g = lane >> 4;
  f32x4 acc[4] = {};
  bf16x8 af[4];
  for (int k = 0; k < 4; k++)
    af[k] = *reinterpret_cast<const bf16x8*>(win + (size_t)(m0 + cc) * 128 + k * 32 + g * 8);
  for (int k = 0; k < 4; k++){
    for (int ct = 0; ct < 4; ct++){
      bf16x8 bf = *reinterpret_cast<const bf16x8*>(wq + (size_t)(c0 + ct * 16 + cc) * 128 + k * 32 + g * 8);
      acc[ct] = mfma16(af[k], bf, acc[ct]);
    }
  }
  for (int ct = 0; ct < 4; ct++){
    int o = c0 + ct * 16 + cc;
    int sec = o >> 7, oo = o & 127, head = oo >> 5, hd = oo & 31;
    float bv = qb[o];
    for (int r = 0; r < 4; r++){
      int m = m0 + g * 4 + r;
      float v = acc[ct][r] + bv;
      int wi = m / NTOK, n = m % NTOK;
      if (sec == 0){
        v *= 0.17677669529663687f;
        Q[((size_t)(wi * 4 + head) * NTP + n) * 32 + hd] = f2bf(v);
      } else if (sec == 1){
        K[((size_t)(wi * 4 + head) * NTP + n) * 32 + hd] = f2bf(v);
      } else {
        Vt[((size_t)(wi * 4 + head) * 32 + hd) * NTP + n] = f2bf(v);
      }
    }
  }
}

// ---------------- K4: windowed flash attention ----------------
__global__ __launch_bounds__(256) void k_attn(const short* __restrict__ Q, const short* __restrict__ K,
                                              const short* __restrict__ Vt, const float* __restrict__ bias,
                                              short* __restrict__ O){
  __shared__ short plds[4][16][56];   // per-wave P tile, 112B row stride (16B-aligned, conflict-light)
  int lane = threadIdx.x & 63, wv = threadIdx.x >> 6;
  int wg = blockIdx.x * 4 + wv;
  int qt = wg % 25; int t2 = wg / 25; int head = t2 & 3; int wi = t2 >> 2;
  int q0 = qt * 16;
  const short* Qb = Q + (size_t)(wi * 4 + head) * NTP * 32;
  const short* Kb = K + (size_t)(wi * 4 + head) * NTP * 32;
  const short* Vb = Vt + (size_t)(wi * 4 + head) * 32 * NTP;
  const float* Bb = bias + (size_t)head * NTOK * NTOK;
  int cc = lane & 15, g = lane >> 4;
  bf16x8 qf = *reinterpret_cast<const bf16x8*>(Qb + (q0 + cc) * 32 + g * 8);
  int irow[4], lbli[4];
  for (int r = 0; r < 4; r++){
    int i = q0 + g * 4 + r; irow[r] = i;
    lbli[r] = swin_label(wi, i < NTOK ? i : NTOK - 1);
  }
  float mrun[4], lrun[4];
  f32x4 acc0 = {}, acc1 = {};
  for (int r = 0; r < 4; r++){ mrun[r] = -1e30f; lrun[r] = 0.f; }
  for (int jt = 0; jt < 13; jt++){
    int j0 = jt * 32;
    int jg0 = j0 + cc, jg1 = j0 + 16 + cc;
    bf16x8 kf0 = *reinterpret_cast<const bf16x8*>(Kb + jg0 * 32 + g * 8);
    bf16x8 kf1 = *reinterpret_cast<const bf16x8*>(Kb + jg1 * 32 + g * 8);
    f32x4 z = {};
    f32x4 s0 = mfma16(qf, kf0, z);
    f32x4 s1 = mfma16(qf, kf1, z);
    int lblj0 = jg0 < NTOK ? swin_label(wi, jg0) : -1;
    int lblj1 = jg1 < NTOK ? swin_label(wi, jg1) : -1;
    for (int r = 0; r < 4; r++){
      int ii = irow[r] < NTOK ? irow[r] : NTOK - 1;
      float v0 = (jg0 < NTOK) ? s0[r] + Bb[(size_t)ii * NTOK + jg0] + (lblj0 != lbli[r] ? -100.f : 0.f) : -1e30f;
      float v1 = (jg1 < NTOK) ? s1[r] + Bb[(size_t)ii * NTOK + jg1] + (lblj1 != lbli[r] ? -100.f : 0.f) : -1e30f;
      float vm = fmaxf(v0, v1);
      #pragma unroll
      for (int off = 1; off < 16; off <<= 1) vm = fmaxf(vm, __shfl_xor(vm, off));
      float mn = fmaxf(mrun[r], vm);
      float al = __expf(mrun[r] - mn);
      float p0 = __expf(v0 - mn), p1 = __expf(v1 - mn);
      float ps = p0 + p1;
      #pragma unroll
      for (int off = 1; off < 16; off <<= 1) ps += __shfl_xor(ps, off);
      lrun[r] = lrun[r] * al + ps;
      mrun[r] = mn;
      acc0[r] *= al; acc1[r] *= al;
      int rr = g * 4 + r;
      plds[wv][rr][cc]      = f2bf(p0);
      plds[wv][rr][cc + 16] = f2bf(p1);
    }
    asm volatile("s_waitcnt lgkmcnt(0)" ::: "memory");
    bf16x8 pf  = *reinterpret_cast<const bf16x8*>(&plds[wv][cc][g * 8]);
    bf16x8 vf0 = *reinterpret_cast<const bf16x8*>(Vb + cc * NTP + j0 + g * 8);
    bf16x8 vf1 = *reinterpret_cast<const bf16x8*>(Vb + (cc + 16) * NTP + j0 + g * 8);
    acc0 = mfma16(pf, vf0, acc0);
    acc1 = mfma16(pf, vf1, acc1);
  }
  for (int r = 0; r < 4; r++){
    int i = irow[r];
    if (i < NTOK){
      float inv = 1.f / lrun[r];
      size_t o = (size_t)(wi * NTOK + i) * 128 + head * 32;
      O[o + cc]      = f2bf(acc0[r] * inv);
      O[o + 16 + cc] = f2bf(acc1[r] * inv);
    }
  }
}

// ---------------- K5: proj GEMM -> projwin bf16 [TOK][128] ----------------
__global__ __launch_bounds__(256) void k_proj(const short* __restrict__ A, const short* __restrict__ Bw,
                                              const float* __restrict__ pb, short* __restrict__ Cout){
  int lane = threadIdx.x & 63, wv = threadIdx.x >> 6;
  int m0 = (blockIdx.x % 1568) * 64 + wv * 16;
  int c0 = (blockIdx.x / 1568) * 64;
  int cc = lane & 15, g = lane >> 4;
  f32x4 acc[4] = {};
  bf16x8 af[4];
  for (int k = 0; k < 4; k++)
    af[k] = *reinterpret_cast<const bf16x8*>(A + (size_t)(m0 + cc) * 128 + k * 32 + g * 8);
  for (int k = 0; k < 4; k++){
    for (int ct = 0; ct < 4; ct++){
      bf16x8 bf = *reinterpret_cast<const bf16x8*>(Bw + (size_t)(c0 + ct * 16 + cc) * 128 + k * 32 + g * 8);
      acc[ct] = mfma16(af[k], bf, acc[ct]);
    }
  }
  for (int ct = 0; ct < 4; ct++){
    int o = c0 + ct * 16 + cc;
    float bv = pb[o];
    for (int r = 0; r < 4; r++){
      int m = m0 + g * 4 + r;
      Cout[(size_t)m * 128 + o] = f2bf(acc[ct][r] + bv);
    }
  }
}

// ---------------- K6: residual1 + LN2 -> d_out (x1) + h2n bf16 [TOK][128] ----------------
__global__ __launch_bounds__(256) void k_res1(const float* __restrict__ x, const short* __restrict__ pwin,
                                              const float* __restrict__ w2, const float* __restrict__ b2,
                                              float* __restrict__ out, short* __restrict__ h2n){
  int m = blockIdx.x * 256 + threadIdx.x;
  int bb = m / SPAT, p = m % SPAT;
  int d = p / 3136, hw = p % 3136, h = hw / 56, wq = hw % 56;
  int dr = (d + 12) & 15, hr = (h + 53) % 56, wr = (wq + 53) % 56;
  int nd = dr >> 3, wd = dr & 7, nh = hr / 7, wh = hr % 7, nw = wr / 7, ww = wr % 7;
  int wi = ((bb * 2 + nd) << 6) + (nh << 3) + nw;
  int n = (wd * 7 + wh) * 7 + ww;
  const float* xp = x + (size_t)bb * 128 * SPAT + p;
  const short* pw = pwin + (size_t)(wi * NTOK + n) * 128;
  float s = 0.f, s2 = 0.f;
  for (int c = 0; c < 128; c++){
    float v = xp[(size_t)c * SPAT] + bf2f(pw[c]);
    s += v; s2 += v * v;
  }
  float mu = s * (1.f / 128.f);
  float var = s2 * (1.f / 128.f) - mu * mu;
  float rs = rsqrtf(var + 1e-5f);
  float* op = out + (size_t)bb * 128 * SPAT + p;
  short* hp = h2n + (size_t)m * 128;
  for (int c = 0; c < 128; c++){
    float v = xp[(size_t)c * SPAT] + bf2f(pw[c]);
    op[(size_t)c * SPAT] = v;
    hp[c] = f2bf((v - mu) * rs * w2[c] + b2[c]);
  }
}

// ---------------- K7: fused FFN (fc1 + gelu + fc2), chunked mid, low LDS ----------------
// 64 tokens/block. Mid (512 ch) processed in 4 chunks of 128 through one 17.4 KB LDS tile.
// fc2 accumulator lives in registers across chunks. Final out tile stored bf16 in the same
// LDS (stride 130 shorts -> (65p + o/2)%32 banks => 2-way = free) for the transposed RMW.
__global__ __launch_bounds__(256) void k_ffn(const short* __restrict__ h2n, const short* __restrict__ w1,
                                             const float* __restrict__ b1, const short* __restrict__ w2,
                                             const float* __restrict__ b2, float* __restrict__ out){
  __shared__ short smid[64 * 136];   // 17408 B total LDS
  int lane = threadIdx.x & 63, wv = threadIdx.x >> 6;
  int t0 = blockIdx.x * 64;
  int cc = lane & 15, g = lane >> 4;
  bf16x8 af[4];
  for (int k = 0; k < 4; k++)
    af[k] = *reinterpret_cast<const bf16x8*>(h2n + (size_t)(t0 + wv * 16 + cc) * 128 + k * 32 + g * 8);
  f32x4 acc2[8] = {};
  for (int c = 0; c < 4; c++){
    // stage 1 chunk: mid[:, c*128 .. c*128+127] = gelu(h2n @ fc1^T + b1)
    for (int ct = 0; ct < 8; ct++){
      f32x4 acc = {};
      int oc = c * 128 + ct * 16 + cc;
      for (int k = 0; k < 4; k++){
        bf16x8 bf = *reinterpret_cast<const bf16x8*>(w1 + (size_t)oc * 128 + k * 32 + g * 8);
        acc = mfma16(af[k], bf, acc);
      }
      float bv = b1[oc];
      for (int r = 0; r < 4; r++){
        int lr = wv * 16 + g * 4 + r;
        float v = acc[r] + bv;
        float t = __expf(1.5957691216057308f * (v + 0.044715f * v * v * v));
        float ge = v * t / (t + 1.f);   // == 0.5v(1+tanh(0.79788456(v+0.044715v^3)))
        smid[lr * 136 + ct * 16 + cc] = f2bf(ge);
      }
    }
    __syncthreads();
    // stage 2 chunk: acc2 += gelu_chunk @ fc2_chunk^T
    for (int ks = 0; ks < 4; ks++){
      bf16x8 a = *reinterpret_cast<const bf16x8*>(&smid[(wv * 16 + cc) * 136 + ks * 32 + g * 8]);
      for (int ct2 = 0; ct2 < 8; ct2++){
        bf16x8 bf = *reinterpret_cast<const bf16x8*>(w2 + (size_t)(ct2 * 16 + cc) * 512 + c * 128 + ks * 32 + g * 8);
        acc2[ct2] = mfma16(a, bf, acc2[ct2]);
      }
    }
    __syncthreads();
  }
  // park out-tile (bf16, stride 130) in LDS for transposed coalesced RMW
  for (int ct = 0; ct < 8; ct++){
    int o = ct * 16 + cc;
    float bv = b2[o];
    for (int r = 0; r < 4; r++){
      int lr = wv * 16 + g * 4 + r;
      smid[lr * 130 + o] = f2bf(acc2[ct][r] + bv);
    }
  }
  __syncthreads();
  int bb = t0 / SPAT, p0 = t0 % SPAT;
  int poff = threadIdx.x & 63;
  int obase = threadIdx.x >> 6;     // 0..3
  float* op = out + (size_t)bb * 128 * SPAT + p0 + poff;
  for (int oi = 0; oi < 32; oi++){
    int o = obase + oi * 4;
    op[(size_t)o * SPAT] += bf2f(smid[poff * 130 + o]);
  }
}

extern "C" void kernel_launch(void* const* d_in, const int* in_sizes, int n_in,
                              void* d_out, int out_size, void* d_ws, size_t ws_size,
                              hipStream_t stream){
  const float* x     = (const float*)d_in[0];
  const float* n1w   = (const float*)d_in[1];
  const float* n1b   = (const float*)d_in[2];
  const float* qkvw  = (const float*)d_in[3];
  const float* qkvb  = (const float*)d_in[4];
  const float* rpb   = (const float*)d_in[5];
  const float* projw = (const float*)d_in[6];
  const float* projb = (const float*)d_in[7];
  const float* n2w   = (const float*)d_in[8];
  const float* n2b   = (const float*)d_in[9];
  const float* fc1w  = (const float*)d_in[10];
  const float* fc1b  = (const float*)d_in[11];
  const float* fc2w  = (const float*)d_in[12];
  const float* fc2b  = (const float*)d_in[13];
  float* out = (float*)d_out;

  char* ws = (char*)d_ws;
  size_t off = 0;
  auto alloc = [&](size_t bytes) -> void* {
    void* p = ws + off;
    off += (bytes + 255) & ~(size_t)255;
    return p;
  };
  short* win  = (short*)alloc((size_t)TOK * 128 * 2);
  short* Obuf = (short*)alloc((size_t)TOK * 128 * 2);
  short* pwin = (short*)alloc((size_t)TOK * 128 * 2);
  short* h2n  = (short*)alloc((size_t)TOK * 128 * 2);
  short* Qb   = (short*)alloc((size_t)1024 * NTP * 32 * 2);
  short* Kb   = (short*)alloc((size_t)1024 * NTP * 32 * 2);
  short* Vtb  = (short*)alloc((size_t)1024 * NTP * 32 * 2);
  float* bias = (float*)alloc((size_t)4 * NTOK * NTOK * 4);
  short* wq   = (short*)alloc(49152 * 2);
  short* wp   = (short*)alloc(16384 * 2);
  short* w1   = (short*)alloc(65536 * 2);
  short* w2   = (short*)alloc(65536 * 2);

  k_convert<<<768, 256, 0, stream>>>(qkvw, projw, fc1w, fc2w, wq, wp, w1, w2);
  k_ln1<<<TOK / 256, 256, 0, stream>>>(x, n1w, n1b, win);
  k_bias<<<(NTOK * NTOK + 255) / 256, 256, 0, stream>>>(rpb, bias);
  k_qkv<<<1568 * 6, 256, 0, stream>>>(win, wq, qkvb, Qb, Kb, Vtb);
  k_attn<<<6400, 256, 0, stream>>>(Qb, Kb, Vtb, bias, Obuf);
  k_proj<<<1568 * 2, 256, 0, stream>>>(Obuf, wp, projb, pwin);
  k_res1<<<TOK / 256, 256, 0, stream>>>(x, pwin, n2w, n2b, out, h2n);
  k_ffn<<<TOK / 64, 256, 0, stream>>>(h2n, w1, fc1b, w2, fc2b, out);
}

// Round 6
// 769.209 us; speedup vs baseline: 1.1377x; 1.0588x over previous
//
#include <hip/hip_runtime.h>

#define DEV __device__ __forceinline__

using bf16x8 = __attribute__((ext_vector_type(8))) __bf16;
using f32x4  = __attribute__((ext_vector_type(4))) float;

namespace {
constexpr int SPAT = 50176;    // 16*56*56
constexpr int TOK  = 100352;   // 2*SPAT
constexpr int NTOK = 392;      // tokens per window
constexpr int NTP  = 416;      // padded token count (26*16)
}

DEV float bf2f(short s){ unsigned u = ((unsigned)(unsigned short)s) << 16; float f; __builtin_memcpy(&f, &u, 4); return f; }
DEV short f2bf(float f){ unsigned u; __builtin_memcpy(&u, &f, 4); u = (u + 0x7fffu + ((u >> 16) & 1u)) >> 16; return (short)u; }
DEV f32x4 mfma16(bf16x8 a, bf16x8 b, f32x4 c){ return __builtin_amdgcn_mfma_f32_16x16x32_bf16(a, b, c, 0, 0, 0); }

// Swin region label for mask: window wi (nd,nh,nw), token n (wd,wh,ww)
DEV int swin_label(int wi, int n){
  int nd = (wi >> 6) & 1, nh = (wi >> 3) & 7, nw = wi & 7;
  int wd = n / 49, wh = (n / 7) % 7, ww = n % 7;
  int d = nd * 8 + wd, h = nh * 7 + wh, w = nw * 7 + ww;
  int ld = d < 8 ? 0 : (d < 12 ? 1 : 2);
  int lh = h < 49 ? 0 : (h < 53 ? 1 : 2);
  int lw = w < 49 ? 0 : (w < 53 ? 1 : 2);
  return ld * 9 + lh * 3 + lw;
}

// ---------------- K0: convert weights fp32 -> bf16 ----------------
__global__ __launch_bounds__(256) void k_convert(const float* __restrict__ qkvw, const float* __restrict__ projw,
                                                 const float* __restrict__ fc1w, const float* __restrict__ fc2w,
                                                 short* __restrict__ wq, short* __restrict__ wp,
                                                 short* __restrict__ w1, short* __restrict__ w2){
  int i = blockIdx.x * 256 + threadIdx.x;
  if (i < 49152)        wq[i]          = f2bf(qkvw[i]);
  else if (i < 65536)   wp[i - 49152]  = f2bf(projw[i - 49152]);
  else if (i < 131072)  w1[i - 65536]  = f2bf(fc1w[i - 65536]);
  else if (i < 196608)  w2[i - 131072] = f2bf(fc2w[i - 131072]);
}

// ---------------- K1: LN1 + roll + window partition -> win bf16 [TOK][128] ----------------
__global__ __launch_bounds__(256) void k_ln1(const float* __restrict__ x, const float* __restrict__ w,
                                             const float* __restrict__ b, short* __restrict__ win){
  int m = blockIdx.x * 256 + threadIdx.x;            // < TOK
  int bb = m / SPAT, p = m % SPAT;
  const float* xp = x + (size_t)bb * 128 * SPAT + p;
  float s = 0.f, s2 = 0.f;
  for (int c = 0; c < 128; c++){ float v = xp[(size_t)c * SPAT]; s += v; s2 += v * v; }
  float mu = s * (1.f / 128.f);
  float var = s2 * (1.f / 128.f) - mu * mu;
  float rs = rsqrtf(var + 1e-5f);
  int d = p / 3136, hw = p % 3136, h = hw / 56, wq = hw % 56;
  int dr = (d + 12) & 15, hr = (h + 53) % 56, wr = (wq + 53) % 56;
  int nd = dr >> 3, wd = dr & 7, nh = hr / 7, wh = hr % 7, nw = wr / 7, ww = wr % 7;
  int wi = ((bb * 2 + nd) << 6) + (nh << 3) + nw;
  int n = (wd * 7 + wh) * 7 + ww;
  short* dst = win + (size_t)(wi * NTOK + n) * 128;
  for (int c = 0; c < 128; c++){
    float v = (xp[(size_t)c * SPAT] - mu) * rs * w[c] + b[c];
    dst[c] = f2bf(v);
  }
}

// ---------------- K2: relative position bias table [4][392][392] ----------------
__global__ __launch_bounds__(256) void k_bias(const float* __restrict__ rpb, float* __restrict__ bias){
  int t = blockIdx.x * 256 + threadIdx.x;
  if (t >= NTOK * NTOK) return;
  int i = t / NTOK, j = t % NTOK;
  int wdi = i / 49, whi = (i / 7) % 7, wwi = i % 7;
  int wdj = j / 49, whj = (j / 7) % 7, wwj = j % 7;
  int idx = (wdi - wdj + 7) * 169 + (whi - whj + 6) * 13 + (wwi - wwj + 6);
  for (int h = 0; h < 4; h++)
    bias[((size_t)h * NTOK + i) * NTOK + j] = rpb[idx * 4 + h];
}

// ---------------- K3: QKV GEMM + scatter into Q/K/Vt ----------------
__global__ __launch_bounds__(256) void k_qkv(const short* __restrict__ win, const short* __restrict__ wq,
                                             const float* __restrict__ qb, short* __restrict__ Q,
                                             short* __restrict__ K, short* __restrict__ Vt){
  int lane = threadIdx.x & 63, wv = threadIdx.x >> 6;
  int m0 = (blockIdx.x % 1568) * 64 + wv * 16;
  int c0 = (blockIdx.x / 1568) * 64;
  int cc = lane & 15, g = lane >> 4;
  f32x4 acc[4] = {};
  bf16x8 af[4];
  for (int k = 0; k < 4; k++)
    af[k] = *reinterpret_cast<const bf16x8*>(win + (size_t)(m0 + cc) * 128 + k * 32 + g * 8);
  for (int k = 0; k < 4; k++){
    for (int ct = 0; ct < 4; ct++){
      bf16x8 bf = *reinterpret_cast<const bf16x8*>(wq + (size_t)(c0 + ct * 16 + cc) * 128 + k * 32 + g * 8);
      acc[ct] = mfma16(af[k], bf, acc[ct]);
    }
  }
  for (int ct = 0; ct < 4; ct++){
    int o = c0 + ct * 16 + cc;
    int sec = o >> 7, oo = o & 127, head = oo >> 5, hd = oo & 31;
    float bv = qb[o];
    for (int r = 0; r < 4; r++){
      int m = m0 + g * 4 + r;
      float v = acc[ct][r] + bv;
      int wi = m / NTOK, n = m % NTOK;
      if (sec == 0){
        v *= 0.17677669529663687f;
        Q[((size_t)(wi * 4 + head) * NTP + n) * 32 + hd] = f2bf(v);
      } else if (sec == 1){
        K[((size_t)(wi * 4 + head) * NTP + n) * 32 + hd] = f2bf(v);
      } else {
        Vt[((size_t)(wi * 4 + head) * 32 + hd) * NTP + n] = f2bf(v);
      }
    }
  }
}

// ---------------- K4: windowed flash attention ----------------
__global__ __launch_bounds__(256) void k_attn(const short* __restrict__ Q, const short* __restrict__ K,
                                              const short* __restrict__ Vt, const float* __restrict__ bias,
                                              short* __restrict__ O){
  __shared__ short plds[4][16][56];   // per-wave P tile, 112B row stride (16B-aligned, conflict-light)
  int lane = threadIdx.x & 63, wv = threadIdx.x >> 6;
  int wg = blockIdx.x * 4 + wv;
  int qt = wg % 25; int t2 = wg / 25; int head = t2 & 3; int wi = t2 >> 2;
  int q0 = qt * 16;
  const short* Qb = Q + (size_t)(wi * 4 + head) * NTP * 32;
  const short* Kb = K + (size_t)(wi * 4 + head) * NTP * 32;
  const short* Vb = Vt + (size_t)(wi * 4 + head) * 32 * NTP;
  const float* Bb = bias + (size_t)head * NTOK * NTOK;
  int cc = lane & 15, g = lane >> 4;
  bf16x8 qf = *reinterpret_cast<const bf16x8*>(Qb + (q0 + cc) * 32 + g * 8);
  int irow[4], lbli[4];
  for (int r = 0; r < 4; r++){
    int i = q0 + g * 4 + r; irow[r] = i;
    lbli[r] = swin_label(wi, i < NTOK ? i : NTOK - 1);
  }
  float mrun[4], lrun[4];
  f32x4 acc0 = {}, acc1 = {};
  for (int r = 0; r < 4; r++){ mrun[r] = -1e30f; lrun[r] = 0.f; }
  for (int jt = 0; jt < 13; jt++){
    int j0 = jt * 32;
    int jg0 = j0 + cc, jg1 = j0 + 16 + cc;
    bf16x8 kf0 = *reinterpret_cast<const bf16x8*>(Kb + jg0 * 32 + g * 8);
    bf16x8 kf1 = *reinterpret_cast<const bf16x8*>(Kb + jg1 * 32 + g * 8);
    f32x4 z = {};
    f32x4 s0 = mfma16(qf, kf0, z);
    f32x4 s1 = mfma16(qf, kf1, z);
    int lblj0 = jg0 < NTOK ? swin_label(wi, jg0) : -1;
    int lblj1 = jg1 < NTOK ? swin_label(wi, jg1) : -1;
    for (int r = 0; r < 4; r++){
      int ii = irow[r] < NTOK ? irow[r] : NTOK - 1;
      float v0 = (jg0 < NTOK) ? s0[r] + Bb[(size_t)ii * NTOK + jg0] + (lblj0 != lbli[r] ? -100.f : 0.f) : -1e30f;
      float v1 = (jg1 < NTOK) ? s1[r] + Bb[(size_t)ii * NTOK + jg1] + (lblj1 != lbli[r] ? -100.f : 0.f) : -1e30f;
      float vm = fmaxf(v0, v1);
      #pragma unroll
      for (int off = 1; off < 16; off <<= 1) vm = fmaxf(vm, __shfl_xor(vm, off));
      float mn = fmaxf(mrun[r], vm);
      float al = __expf(mrun[r] - mn);
      float p0 = __expf(v0 - mn), p1 = __expf(v1 - mn);
      float ps = p0 + p1;
      #pragma unroll
      for (int off = 1; off < 16; off <<= 1) ps += __shfl_xor(ps, off);
      lrun[r] = lrun[r] * al + ps;
      mrun[r] = mn;
      acc0[r] *= al; acc1[r] *= al;
      int rr = g * 4 + r;
      plds[wv][rr][cc]      = f2bf(p0);
      plds[wv][rr][cc + 16] = f2bf(p1);
    }
    asm volatile("s_waitcnt lgkmcnt(0)" ::: "memory");
    bf16x8 pf  = *reinterpret_cast<const bf16x8*>(&plds[wv][cc][g * 8]);
    bf16x8 vf0 = *reinterpret_cast<const bf16x8*>(Vb + cc * NTP + j0 + g * 8);
    bf16x8 vf1 = *reinterpret_cast<const bf16x8*>(Vb + (cc + 16) * NTP + j0 + g * 8);
    acc0 = mfma16(pf, vf0, acc0);
    acc1 = mfma16(pf, vf1, acc1);
  }
  for (int r = 0; r < 4; r++){
    int i = irow[r];
    if (i < NTOK){
      float inv = 1.f / lrun[r];
      size_t o = (size_t)(wi * NTOK + i) * 128 + head * 32;
      O[o + cc]      = f2bf(acc0[r] * inv);
      O[o + 16 + cc] = f2bf(acc1[r] * inv);
    }
  }
}

// ---------------- K5: proj GEMM -> projwin bf16 [TOK][128] ----------------
__global__ __launch_bounds__(256) void k_proj(const short* __restrict__ A, const short* __restrict__ Bw,
                                              const float* __restrict__ pb, short* __restrict__ Cout){
  int lane = threadIdx.x & 63, wv = threadIdx.x >> 6;
  int m0 = (blockIdx.x % 1568) * 64 + wv * 16;
  int c0 = (blockIdx.x / 1568) * 64;
  int cc = lane & 15, g = lane >> 4;
  f32x4 acc[4] = {};
  bf16x8 af[4];
  for (int k = 0; k < 4; k++)
    af[k] = *reinterpret_cast<const bf16x8*>(A + (size_t)(m0 + cc) * 128 + k * 32 + g * 8);
  for (int k = 0; k < 4; k++){
    for (int ct = 0; ct < 4; ct++){
      bf16x8 bf = *reinterpret_cast<const bf16x8*>(Bw + (size_t)(c0 + ct * 16 + cc) * 128 + k * 32 + g * 8);
      acc[ct] = mfma16(af[k], bf, acc[ct]);
    }
  }
  for (int ct = 0; ct < 4; ct++){
    int o = c0 + ct * 16 + cc;
    float bv = pb[o];
    for (int r = 0; r < 4; r++){
      int m = m0 + g * 4 + r;
      Cout[(size_t)m * 128 + o] = f2bf(acc[ct][r] + bv);
    }
  }
}

// ---------------- K6: residual1 + LN2 -> d_out (x1) + h2n bf16 [TOK][128] ----------------
__global__ __launch_bounds__(256) void k_res1(const float* __restrict__ x, const short* __restrict__ pwin,
                                              const float* __restrict__ w2, const float* __restrict__ b2,
                                              float* __restrict__ out, short* __restrict__ h2n){
  int m = blockIdx.x * 256 + threadIdx.x;
  int bb = m / SPAT, p = m % SPAT;
  int d = p / 3136, hw = p % 3136, h = hw / 56, wq = hw % 56;
  int dr = (d + 12) & 15, hr = (h + 53) % 56, wr = (wq + 53) % 56;
  int nd = dr >> 3, wd = dr & 7, nh = hr / 7, wh = hr % 7, nw = wr / 7, ww = wr % 7;
  int wi = ((bb * 2 + nd) << 6) + (nh << 3) + nw;
  int n = (wd * 7 + wh) * 7 + ww;
  const float* xp = x + (size_t)bb * 128 * SPAT + p;
  const short* pw = pwin + (size_t)(wi * NTOK + n) * 128;
  float s = 0.f, s2 = 0.f;
  for (int c = 0; c < 128; c++){
    float v = xp[(size_t)c * SPAT] + bf2f(pw[c]);
    s += v; s2 += v * v;
  }
  float mu = s * (1.f / 128.f);
  float var = s2 * (1.f / 128.f) - mu * mu;
  float rs = rsqrtf(var + 1e-5f);
  float* op = out + (size_t)bb * 128 * SPAT + p;
  short* hp = h2n + (size_t)m * 128;
  for (int c = 0; c < 128; c++){
    float v = xp[(size_t)c * SPAT] + bf2f(pw[c]);
    op[(size_t)c * SPAT] = v;
    hp[c] = f2bf((v - mu) * rs * w2[c] + b2[c]);
  }
}

// ---------------- K7: fused FFN (fc1 + gelu + fc2), ILP-restructured ----------------
// 128 tokens/block, 4 waves x 2 m-tiles each. Mid (512) in 4 chunks of 128 through one
// 34.8 KB LDS tile. Stage-1 k-outer/(ct,m)-inner: 16 independent MFMA chains per k-step;
// each weight fragment feeds 2 MFMAs (register reuse). fc2 acc in registers across chunks.
__global__ __launch_bounds__(256) void k_ffn(const short* __restrict__ h2n, const short* __restrict__ w1,
                                             const float* __restrict__ b1, const short* __restrict__ w2,
                                             const float* __restrict__ b2, float* __restrict__ out){
  __shared__ short smid[128 * 136];   // 34816 B
  int lane = threadIdx.x & 63, wv = threadIdx.x >> 6;
  int t0 = blockIdx.x * 128;
  int cc = lane & 15, g = lane >> 4;
  bf16x8 af[2][4];
  for (int m = 0; m < 2; m++)
    for (int k = 0; k < 4; k++)
      af[m][k] = *reinterpret_cast<const bf16x8*>(h2n + (size_t)(t0 + wv * 32 + m * 16 + cc) * 128 + k * 32 + g * 8);
  f32x4 acc2[8][2] = {};
  for (int c = 0; c < 4; c++){
    // stage 1 chunk: 16 independent accs, k-outer
    f32x4 acc1[8][2] = {};
    for (int k = 0; k < 4; k++){
      #pragma unroll
      for (int ct = 0; ct < 8; ct++){
        bf16x8 bf = *reinterpret_cast<const bf16x8*>(w1 + (size_t)(c * 128 + ct * 16 + cc) * 128 + k * 32 + g * 8);
        acc1[ct][0] = mfma16(af[0][k], bf, acc1[ct][0]);
        acc1[ct][1] = mfma16(af[1][k], bf, acc1[ct][1]);
      }
    }
    if (c) __syncthreads();   // prev chunk's stage-2 reads must finish before overwrite
    #pragma unroll
    for (int ct = 0; ct < 8; ct++){
      float bv = b1[c * 128 + ct * 16 + cc];
      for (int m = 0; m < 2; m++)
        for (int r = 0; r < 4; r++){
          int lr = wv * 32 + m * 16 + g * 4 + r;
          float v = acc1[ct][m][r] + bv;
          float t = __expf(1.5957691216057308f * (v + 0.044715f * v * v * v));
          smid[lr * 136 + ct * 16 + cc] = f2bf(v * t / (t + 1.f));   // tanh-approx gelu
        }
    }
    __syncthreads();
    // stage 2 chunk: acc2 += gelu_chunk @ fc2_chunk^T (16 independent accs per ks)
    for (int ks = 0; ks < 4; ks++){
      bf16x8 a0 = *reinterpret_cast<const bf16x8*>(&smid[(wv * 32 + cc) * 136 + ks * 32 + g * 8]);
      bf16x8 a1 = *reinterpret_cast<const bf16x8*>(&smid[(wv * 32 + 16 + cc) * 136 + ks * 32 + g * 8]);
      #pragma unroll
      for (int ct = 0; ct < 8; ct++){
        bf16x8 bf = *reinterpret_cast<const bf16x8*>(w2 + (size_t)(ct * 16 + cc) * 512 + c * 128 + ks * 32 + g * 8);
        acc2[ct][0] = mfma16(a0, bf, acc2[ct][0]);
        acc2[ct][1] = mfma16(a1, bf, acc2[ct][1]);
      }
    }
  }
  __syncthreads();
  // park out-tile (bf16, stride 130 -> 2-way-free banks) for transposed coalesced RMW
  for (int ct = 0; ct < 8; ct++){
    float bv = b2[ct * 16 + cc];
    for (int m = 0; m < 2; m++)
      for (int r = 0; r < 4; r++){
        int lr = wv * 32 + m * 16 + g * 4 + r;
        smid[lr * 130 + ct * 16 + cc] = f2bf(acc2[ct][m][r] + bv);
      }
  }
  __syncthreads();
  int bb = t0 / SPAT, p0 = t0 % SPAT;
  int poff = threadIdx.x & 127;
  int obase = threadIdx.x >> 7;     // 0..1
  float* op = out + (size_t)bb * 128 * SPAT + p0 + poff;
  for (int oi = 0; oi < 64; oi++){
    int o = obase + oi * 2;
    op[(size_t)o * SPAT] += bf2f(smid[poff * 130 + o]);
  }
}

extern "C" void kernel_launch(void* const* d_in, const int* in_sizes, int n_in,
                              void* d_out, int out_size, void* d_ws, size_t ws_size,
                              hipStream_t stream){
  const float* x     = (const float*)d_in[0];
  const float* n1w   = (const float*)d_in[1];
  const float* n1b   = (const float*)d_in[2];
  const float* qkvw  = (const float*)d_in[3];
  const float* qkvb  = (const float*)d_in[4];
  const float* rpb   = (const float*)d_in[5];
  const float* projw = (const float*)d_in[6];
  const float* projb = (const float*)d_in[7];
  const float* n2w   = (const float*)d_in[8];
  const float* n2b   = (const float*)d_in[9];
  const float* fc1w  = (const float*)d_in[10];
  const float* fc1b  = (const float*)d_in[11];
  const float* fc2w  = (const float*)d_in[12];
  const float* fc2b  = (const float*)d_in[13];
  float* out = (float*)d_out;

  char* ws = (char*)d_ws;
  size_t off = 0;
  auto alloc = [&](size_t bytes) -> void* {
    void* p = ws + off;
    off += (bytes + 255) & ~(size_t)255;
    return p;
  };
  short* win  = (short*)alloc((size_t)TOK * 128 * 2);
  short* Obuf = (short*)alloc((size_t)TOK * 128 * 2);
  short* pwin = (short*)alloc((size_t)TOK * 128 * 2);
  short* h2n  = (short*)alloc((size_t)TOK * 128 * 2);
  short* Qb   = (short*)alloc((size_t)1024 * NTP * 32 * 2);
  short* Kb   = (short*)alloc((size_t)1024 * NTP * 32 * 2);
  short* Vtb  = (short*)alloc((size_t)1024 * NTP * 32 * 2);
  float* bias = (float*)alloc((size_t)4 * NTOK * NTOK * 4);
  short* wq   = (short*)alloc(49152 * 2);
  short* wp   = (short*)alloc(16384 * 2);
  short* w1   = (short*)alloc(65536 * 2);
  short* w2   = (short*)alloc(65536 * 2);

  k_convert<<<768, 256, 0, stream>>>(qkvw, projw, fc1w, fc2w, wq, wp, w1, w2);
  k_ln1<<<TOK / 256, 256, 0, stream>>>(x, n1w, n1b, win);
  k_bias<<<(NTOK * NTOK + 255) / 256, 256, 0, stream>>>(rpb, bias);
  k_qkv<<<1568 * 6, 256, 0, stream>>>(win, wq, qkvb, Qb, Kb, Vtb);
  k_attn<<<6400, 256, 0, stream>>>(Qb, Kb, Vtb, bias, Obuf);
  k_proj<<<1568 * 2, 256, 0, stream>>>(Obuf, wp, projb, pwin);
  k_res1<<<TOK / 256, 256, 0, stream>>>(x, pwin, n2w, n2b, out, h2n);
  k_ffn<<<TOK / 128, 256, 0, stream>>>(h2n, w1, fc1b, w2, fc2b, out);
}

// Round 12
// 717.283 us; speedup vs baseline: 1.2201x; 1.0724x over previous
//
#include <hip/hip_runtime.h>

#define DEV __device__ __forceinline__

using bf16x8 = __attribute__((ext_vector_type(8))) __bf16;
using f32x4  = __attribute__((ext_vector_type(4))) float;
using short8 = __attribute__((ext_vector_type(8))) short;

namespace {
constexpr int SPAT = 50176;    // 16*56*56
constexpr int TOK  = 100352;   // 2*SPAT
constexpr int NTOK = 392;      // tokens per window
constexpr int NTP  = 416;      // padded token count (26*16)
}

DEV float bf2f(short s){ unsigned u = ((unsigned)(unsigned short)s) << 16; float f; __builtin_memcpy(&f, &u, 4); return f; }
DEV short f2bf(float f){ unsigned u; __builtin_memcpy(&u, &f, 4); u = (u + 0x7fffu + ((u >> 16) & 1u)) >> 16; return (short)u; }
DEV f32x4 mfma16(bf16x8 a, bf16x8 b, f32x4 c){ return __builtin_amdgcn_mfma_f32_16x16x32_bf16(a, b, c, 0, 0, 0); }

DEV int swin_label(int wi, int n){
  int nd = (wi >> 6) & 1, nh = (wi >> 3) & 7, nw = wi & 7;
  int wd = n / 49, wh = (n / 7) % 7, ww = n % 7;
  int d = nd * 8 + wd, h = nh * 7 + wh, w = nw * 7 + ww;
  int ld = d < 8 ? 0 : (d < 12 ? 1 : 2);
  int lh = h < 49 ? 0 : (h < 53 ? 1 : 2);
  int lw = w < 49 ? 0 : (w < 53 ? 1 : 2);
  return ld * 9 + lh * 3 + lw;
}

DEV void roll_map(int bb, int p, int& wi, int& n){
  int d = p / 3136, hw = p % 3136, h = hw / 56, wq = hw % 56;
  int dr = (d + 12) & 15, hr = (h + 53) % 56, wr = (wq + 53) % 56;
  int nd = dr >> 3, wd = dr & 7, nh = hr / 7, wh = hr % 7, nw = wr / 7, ww = wr % 7;
  wi = ((bb * 2 + nd) << 6) + (nh << 3) + nw;
  n = (wd * 7 + wh) * 7 + ww;
}

__global__ __launch_bounds__(256) void k_convert(const float* __restrict__ qkvw, const float* __restrict__ projw,
                                                 const float* __restrict__ fc1w, const float* __restrict__ fc2w,
                                                 short* __restrict__ wq, short* __restrict__ wp,
                                                 short* __restrict__ w1, short* __restrict__ w2){
  int i = blockIdx.x * 256 + threadIdx.x;
  if (i < 49152)        wq[i]          = f2bf(qkvw[i]);
  else if (i < 65536)   wp[i - 49152]  = f2bf(projw[i - 49152]);
  else if (i < 131072)  w1[i - 65536]  = f2bf(fc1w[i - 65536]);
  else if (i < 196608)  w2[i - 131072] = f2bf(fc2w[i - 131072]);
}

__global__ __launch_bounds__(256) void k_ln1(const float* __restrict__ x, const float* __restrict__ w,
                                             const float* __restrict__ b, short* __restrict__ win){
  __shared__ float xs[128 * 68];
  __shared__ float wln[128], bln[128];
  int t = threadIdx.x;
  int p0g = blockIdx.x * 64;
  int bb = p0g / SPAT, ps = p0g % SPAT;
  const float* xb = x + (size_t)bb * 128 * SPAT + ps;
  int chunk = t & 15, crow = t >> 4;
  for (int it = 0; it < 8; it++){
    int c = it * 16 + crow;
    f32x4 v = *reinterpret_cast<const f32x4*>(xb + (size_t)c * SPAT + chunk * 4);
    *reinterpret_cast<f32x4*>(&xs[c * 68 + chunk * 4]) = v;
  }
  if (t < 128){ wln[t] = w[t]; bln[t] = b[t]; }
  __syncthreads();
  int tl = t >> 2, part = t & 3;
  float s = 0.f, s2 = 0.f;
  for (int i = 0; i < 32; i++){
    float v = xs[(part * 32 + i) * 68 + tl];
    s += v; s2 += v * v;
  }
  s  += __shfl_xor(s, 1);  s  += __shfl_xor(s, 2);
  s2 += __shfl_xor(s2, 1); s2 += __shfl_xor(s2, 2);
  float mu = s * (1.f / 128.f);
  float var = s2 * (1.f / 128.f) - mu * mu;
  float rs = rsqrtf(var + 1e-5f);
  int wi, n; roll_map(bb, ps + tl, wi, n);
  short* dst = win + (size_t)(wi * NTOK + n) * 128 + part * 32;
  #pragma unroll
  for (int k8 = 0; k8 < 4; k8++){
    short8 o;
    #pragma unroll
    for (int j = 0; j < 8; j++){
      int c = part * 32 + k8 * 8 + j;
      o[j] = f2bf((xs[c * 68 + tl] - mu) * rs * wln[c] + bln[c]);
    }
    *reinterpret_cast<short8*>(dst + k8 * 8) = o;
  }
}

__global__ __launch_bounds__(256) void k_bias(const float* __restrict__ rpb, float* __restrict__ bias){
  int t = blockIdx.x * 256 + threadIdx.x;
  if (t >= NTOK * NTOK) return;
  int i = t / NTOK, j = t % NTOK;
  int wdi = i / 49, whi = (i / 7) % 7, wwi = i % 7;
  int wdj = j / 49, whj = (j / 7) % 7, wwj = j % 7;
  int idx = (wdi - wdj + 7) * 169 + (whi - whj + 6) * 13 + (wwi - wwj + 6);
  for (int h = 0; h < 4; h++)
    bias[((size_t)h * NTOK + i) * NTOK + j] = rpb[idx * 4 + h];
}

__global__ __launch_bounds__(256) void k_qkv(const short* __restrict__ win, const short* __restrict__ wq,
                                             const float* __restrict__ qb, short* __restrict__ Q,
                                             short* __restrict__ K, short* __restrict__ Vt){
  int lane = threadIdx.x & 63, wv = threadIdx.x >> 6;
  int m0 = (blockIdx.x % 1568) * 64 + wv * 16;
  int c0 = (blockIdx.x / 1568) * 64;
  int cc = lane & 15, g = lane >> 4;
  f32x4 acc[4] = {};
  bf16x8 af[4];
  for (int k = 0; k < 4; k++)
    af[k] = *reinterpret_cast<const bf16x8*>(win + (size_t)(m0 + cc) * 128 + k * 32 + g * 8);
  for (int k = 0; k < 4; k++){
    for (int ct = 0; ct < 4; ct++){
      bf16x8 bf = *reinterpret_cast<const bf16x8*>(wq + (size_t)(c0 + ct * 16 + cc) * 128 + k * 32 + g * 8);
      acc[ct] = mfma16(af[k], bf, acc[ct]);
    }
  }
  for (int ct = 0; ct < 4; ct++){
    int o = c0 + ct * 16 + cc;
    int sec = o >> 7, oo = o & 127, head = oo >> 5, hd = oo & 31;
    float bv = qb[o];
    for (int r = 0; r < 4; r++){
      int m = m0 + g * 4 + r;
      float v = acc[ct][r] + bv;
      int wi = m / NTOK, n = m % NTOK;
      if (sec == 0){
        v *= 0.17677669529663687f;
        Q[((size_t)(wi * 4 + head) * NTP + n) * 32 + hd] = f2bf(v);
      } else if (sec == 1){
        K[((size_t)(wi * 4 + head) * NTP + n) * 32 + hd] = f2bf(v);
      } else {
        Vt[((size_t)(wi * 4 + head) * 32 + hd) * NTP + n] = f2bf(v);
      }
    }
  }
}

__global__ __launch_bounds__(256) void k_attn(const short* __restrict__ Q, const short* __restrict__ K,
                                              const short* __restrict__ Vt, const float* __restrict__ bias,
                                              short* __restrict__ O){
  __shared__ short plds[4][16][56];
  int lane = threadIdx.x & 63, wv = threadIdx.x >> 6;
  int wg = blockIdx.x * 4 + wv;
  int qt = wg % 25; int t2 = wg / 25; int head = t2 & 3; int wi = t2 >> 2;
  int q0 = qt * 16;
  const short* Qb = Q + (size_t)(wi * 4 + head) * NTP * 32;
  const short* Kb = K + (size_t)(wi * 4 + head) * NTP * 32;
  const short* Vb = Vt + (size_t)(wi * 4 + head) * 32 * NTP;
  const float* Bb = bias + (size_t)head * NTOK * NTOK;
  int cc = lane & 15, g = lane >> 4;
  bf16x8 qf = *reinterpret_cast<const bf16x8*>(Qb + (q0 + cc) * 32 + g * 8);
  int irow[4], lbli[4];
  for (int r = 0; r < 4; r++){
    int i = q0 + g * 4 + r; irow[r] = i;
    lbli[r] = swin_label(wi, i < NTOK ? i : NTOK - 1);
  }
  float mrun[4], lrun[4];
  f32x4 acc0 = {}, acc1 = {};
  for (int r = 0; r < 4; r++){ mrun[r] = -1e30f; lrun[r] = 0.f; }
  for (int jt = 0; jt < 13; jt++){
    int j0 = jt * 32;
    int jg0 = j0 + cc, jg1 = j0 + 16 + cc;
    bf16x8 kf0 = *reinterpret_cast<const bf16x8*>(Kb + jg0 * 32 + g * 8);
    bf16x8 kf1 = *reinterpret_cast<const bf16x8*>(Kb + jg1 * 32 + g * 8);
    f32x4 z = {};
    f32x4 s0 = mfma16(qf, kf0, z);
    f32x4 s1 = mfma16(qf, kf1, z);
    int lblj0 = jg0 < NTOK ? swin_label(wi, jg0) : -1;
    int lblj1 = jg1 < NTOK ? swin_label(wi, jg1) : -1;
    for (int r = 0; r < 4; r++){
      int ii = irow[r] < NTOK ? irow[r] : NTOK - 1;
      float v0 = (jg0 < NTOK) ? s0[r] + Bb[(size_t)ii * NTOK + jg0] + (lblj0 != lbli[r] ? -100.f : 0.f) : -1e30f;
      float v1 = (jg1 < NTOK) ? s1[r] + Bb[(size_t)ii * NTOK + jg1] + (lblj1 != lbli[r] ? -100.f : 0.f) : -1e30f;
      float vm = fmaxf(v0, v1);
      #pragma unroll
      for (int off = 1; off < 16; off <<= 1) vm = fmaxf(vm, __shfl_xor(vm, off));
      float mn = fmaxf(mrun[r], vm);
      float al = __expf(mrun[r] - mn);
      float p0 = __expf(v0 - mn), p1 = __expf(v1 - mn);
      float ps = p0 + p1;
      #pragma unroll
      for (int off = 1; off < 16; off <<= 1) ps += __shfl_xor(ps, off);
      lrun[r] = lrun[r] * al + ps;
      mrun[r] = mn;
      acc0[r] *= al; acc1[r] *= al;
      int rr = g * 4 + r;
      plds[wv][rr][cc]      = f2bf(p0);
      plds[wv][rr][cc + 16] = f2bf(p1);
    }
    asm volatile("s_waitcnt lgkmcnt(0)" ::: "memory");
    bf16x8 pf  = *reinterpret_cast<const bf16x8*>(&plds[wv][cc][g * 8]);
    bf16x8 vf0 = *reinterpret_cast<const bf16x8*>(Vb + cc * NTP + j0 + g * 8);
    bf16x8 vf1 = *reinterpret_cast<const bf16x8*>(Vb + (cc + 16) * NTP + j0 + g * 8);
    acc0 = mfma16(pf, vf0, acc0);
    acc1 = mfma16(pf, vf1, acc1);
  }
  for (int r = 0; r < 4; r++){
    int i = irow[r];
    if (i < NTOK){
      float inv = 1.f / lrun[r];
      size_t o = (size_t)(wi * NTOK + i) * 128 + head * 32;
      O[o + cc]      = f2bf(acc0[r] * inv);
      O[o + 16 + cc] = f2bf(acc1[r] * inv);
    }
  }
}

__global__ __launch_bounds__(256) void k_proj(const short* __restrict__ A, const short* __restrict__ Bw,
                                              const float* __restrict__ pb, short* __restrict__ Cout){
  int lane = threadIdx.x & 63, wv = threadIdx.x >> 6;
  int m0 = (blockIdx.x % 1568) * 64 + wv * 16;
  int c0 = (blockIdx.x / 1568) * 64;
  int cc = lane & 15, g = lane >> 4;
  f32x4 acc[4] = {};
  bf16x8 af[4];
  for (int k = 0; k < 4; k++)
    af[k] = *reinterpret_cast<const bf16x8*>(A + (size_t)(m0 + cc) * 128 + k * 32 + g * 8);
  for (int k = 0; k < 4; k++){
    for (int ct = 0; ct < 4; ct++){
      bf16x8 bf = *reinterpret_cast<const bf16x8*>(Bw + (size_t)(c0 + ct * 16 + cc) * 128 + k * 32 + g * 8);
      acc[ct] = mfma16(af[k], bf, acc[ct]);
    }
  }
  for (int ct = 0; ct < 4; ct++){
    int o = c0 + ct * 16 + cc;
    float bv = pb[o];
    for (int r = 0; r < 4; r++){
      int m = m0 + g * 4 + r;
      Cout[(size_t)m * 128 + o] = f2bf(acc[ct][r] + bv);
    }
  }
}

__global__ __launch_bounds__(256) void k_res1(const float* __restrict__ x, const short* __restrict__ pwin,
                                              const float* __restrict__ w2, const float* __restrict__ b2,
                                              float* __restrict__ out, short* __restrict__ h2n){
  __shared__ float xs[128 * 68];
  __shared__ float wln[128], bln[128];
  int t = threadIdx.x;
  int p0g = blockIdx.x * 64;
  int bb = p0g / SPAT, ps = p0g % SPAT;
  const float* xb = x + (size_t)bb * 128 * SPAT + ps;
  int chunk = t & 15, crow = t >> 4;
  for (int it = 0; it < 8; it++){
    int c = it * 16 + crow;
    f32x4 v = *reinterpret_cast<const f32x4*>(xb + (size_t)c * SPAT + chunk * 4);
    *reinterpret_cast<f32x4*>(&xs[c * 68 + chunk * 4]) = v;
  }
  if (t < 128){ wln[t] = w2[t]; bln[t] = b2[t]; }
  __syncthreads();
  for (int it = 0; it < 4; it++){
    int r = it * 16 + crow;
    int wi, n; roll_map(bb, ps + r, wi, n);
    short8 pv = *reinterpret_cast<const short8*>(pwin + (size_t)(wi * NTOK + n) * 128 + chunk * 8);
    #pragma unroll
    for (int j = 0; j < 8; j++)
      xs[(chunk * 8 + j) * 68 + r] += bf2f(pv[j]);
  }
  __syncthreads();
  float* ob = out + (size_t)bb * 128 * SPAT + ps;
  for (int it = 0; it < 8; it++){
    int c = it * 16 + crow;
    f32x4 v = *reinterpret_cast<f32x4*>(&xs[c * 68 + chunk * 4]);
    *reinterpret_cast<f32x4*>(ob + (size_t)c * SPAT + chunk * 4) = v;
  }
  int tl = t >> 2, part = t & 3;
  float s = 0.f, s2 = 0.f;
  for (int i = 0; i < 32; i++){
    float v = xs[(part * 32 + i) * 68 + tl];
    s += v; s2 += v * v;
  }
  s  += __shfl_xor(s, 1);  s  += __shfl_xor(s, 2);
  s2 += __shfl_xor(s2, 1); s2 += __shfl_xor(s2, 2);
  float mu = s * (1.f / 128.f);
  float var = s2 * (1.f / 128.f) - mu * mu;
  float rs = rsqrtf(var + 1e-5f);
  short* hp = h2n + (size_t)(p0g + tl) * 128 + part * 32;
  #pragma unroll
  for (int k8 = 0; k8 < 4; k8++){
    short8 o;
    #pragma unroll
    for (int j = 0; j < 8; j++){
      int c = part * 32 + k8 * 8 + j;
      o[j] = f2bf((xs[c * 68 + tl] - mu) * rs * wln[c] + bln[c]);
    }
    *reinterpret_cast<short8*>(hp + k8 * 8) = o;
  }
}

__global__ __launch_bounds__(256) void k_fc1(const short* __restrict__ h2n, const short* __restrict__ w1,
                                             const float* __restrict__ b1, short* __restrict__ mid){
  __shared__ short smid[64 * 136];
  int t = threadIdx.x, lane = t & 63, wv = t >> 6;
  int t0 = (blockIdx.x >> 2) * 64, c0 = (blockIdx.x & 3) * 128;
  int cc = lane & 15, g = lane >> 4;
  int m0 = t0 + wv * 16;
  bf16x8 af[4];
  for (int k = 0; k < 4; k++)
    af[k] = *reinterpret_cast<const bf16x8*>(h2n + (size_t)(m0 + cc) * 128 + k * 32 + g * 8);
  f32x4 acc[8] = {};
  for (int k = 0; k < 4; k++){
    #pragma unroll
    for (int ct = 0; ct < 8; ct++){
      bf16x8 bf = *reinterpret_cast<const bf16x8*>(w1 + (size_t)(c0 + ct * 16 + cc) * 128 + k * 32 + g * 8);
      acc[ct] = mfma16(af[k], bf, acc[ct]);
    }
  }
  #pragma unroll
  for (int ct = 0; ct < 8; ct++){
    float bv = b1[c0 + ct * 16 + cc];
    for (int r = 0; r < 4; r++){
      int lr = wv * 16 + g * 4 + r;
      float v = acc[ct][r] + bv;
      float e = __expf(1.5957691216057308f * (v + 0.044715f * v * v * v));
      smid[lr * 136 + ct * 16 + cc] = f2bf(v * e / (e + 1.f));
    }
  }
  __syncthreads();
  int chunk = t & 15, row = t >> 4;
  for (int it = 0; it < 4; it++){
    int r = it * 16 + row;
    short8 v = *reinterpret_cast<short8*>(&smid[r * 136 + chunk * 8]);
    *reinterpret_cast<short8*>(mid + (size_t)(t0 + r) * 512 + c0 + chunk * 8) = v;
  }
}

__global__ __launch_bounds__(256) void k_fc2(const short* __restrict__ mid, const short* __restrict__ w2,
                                             const float* __restrict__ b2, float* __restrict__ out){
  __shared__ short so[64 * 130];
  int t = threadIdx.x, lane = t & 63, wv = t >> 6;
  int t0 = blockIdx.x * 64;
  int cc = lane & 15, g = lane >> 4;
  int m0 = t0 + wv * 16;
  f32x4 acc[8] = {};
  for (int ks = 0; ks < 16; ks++){
    bf16x8 a = *reinterpret_cast<const bf16x8*>(mid + (size_t)(m0 + cc) * 512 + ks * 32 + g * 8);
    #pragma unroll
    for (int ct = 0; ct < 8; ct++){
      bf16x8 bf = *reinterpret_cast<const bf16x8*>(w2 + (size_t)(ct * 16 + cc) * 512 + ks * 32 + g * 8);
      acc[ct] = mfma16(a, bf, acc[ct]);
    }
  }
  #pragma unroll
  for (int ct = 0; ct < 8; ct++){
    float bv = b2[ct * 16 + cc];
    for (int r = 0; r < 4; r++){
      int lr = wv * 16 + g * 4 + r;
      so[lr * 130 + ct * 16 + cc] = f2bf(acc[ct][r] + bv);
    }
  }
  __syncthreads();
  int bb = t0 / SPAT, ps = t0 % SPAT;
  int poff = t & 63, obase = t >> 6;
  float* op = out + (size_t)bb * 128 * SPAT + ps + poff;
  for (int oi = 0; oi < 32; oi++){
    int o = obase + oi * 4;
    op[(size_t)o * SPAT] += bf2f(so[poff * 130 + o]);
  }
}

extern "C" void kernel_launch(void* const* d_in, const int* in_sizes, int n_in,
                              void* d_out, int out_size, void* d_ws, size_t ws_size,
                              hipStream_t stream){
  const float* x     = (const float*)d_in[0];
  const float* n1w   = (const float*)d_in[1];
  const float* n1b   = (const float*)d_in[2];
  const float* qkvw  = (const float*)d_in[3];
  const float* qkvb  = (const float*)d_in[4];
  const float* rpb   = (const float*)d_in[5];
  const float* projw = (const float*)d_in[6];
  const float* projb = (const float*)d_in[7];
  const float* n2w   = (const float*)d_in[8];
  const float* n2b   = (const float*)d_in[9];
  const float* fc1w  = (const float*)d_in[10];
  const float* fc1b  = (const float*)d_in[11];
  const float* fc2w  = (const float*)d_in[12];
  const float* fc2b  = (const float*)d_in[13];
  float* out = (float*)d_out;

  char* ws = (char*)d_ws;
  size_t off = 0;
  auto alloc = [&](size_t bytes) -> void* {
    void* p = ws + off;
    off += (bytes + 255) & ~(size_t)255;
    return p;
  };
  short* pwin = (short*)alloc((size_t)TOK * 128 * 2);
  short* h2n  = (short*)alloc((size_t)TOK * 128 * 2);
  float* bias = (float*)alloc((size_t)4 * NTOK * NTOK * 4);
  short* wq   = (short*)alloc(49152 * 2);
  short* wp   = (short*)alloc(16384 * 2);
  short* w1   = (short*)alloc(65536 * 2);
  short* w2   = (short*)alloc(65536 * 2);
  // region dead after k_proj/k_attn — reused by mid (TOK*512*2 = 102.8 MB <= ~106 MB)
  short* win  = (short*)alloc((size_t)TOK * 128 * 2);
  short* Obuf = (short*)alloc((size_t)TOK * 128 * 2);
  short* Qb   = (short*)alloc((size_t)1024 * NTP * 32 * 2);
  short* Kb   = (short*)alloc((size_t)1024 * NTP * 32 * 2);
  short* Vtb  = (short*)alloc((size_t)1024 * NTP * 32 * 2);
  short* mid  = win;   // alias over win..Kb (all dead before k_fc1)

  k_convert<<<768, 256, 0, stream>>>(qkvw, projw, fc1w, fc2w, wq, wp, w1, w2);
  k_ln1<<<TOK / 64, 256, 0, stream>>>(x, n1w, n1b, win);
  k_bias<<<(NTOK * NTOK + 255) / 256, 256, 0, stream>>>(rpb, bias);
  k_qkv<<<1568 * 6, 256, 0, stream>>>(win, wq, qkvb, Qb, Kb, Vtb);
  k_attn<<<6400, 256, 0, stream>>>(Qb, Kb, Vtb, bias, Obuf);
  k_proj<<<1568 * 2, 256, 0, stream>>>(Obuf, wp, projb, pwin);
  k_res1<<<TOK / 64, 256, 0, stream>>>(x, pwin, n2w, n2b, out, h2n);
  k_fc1<<<1568 * 4, 256, 0, stream>>>(h2n, w1, fc1b, mid);
  k_fc2<<<1568, 256, 0, stream>>>(mid, w2, fc2b, out);
}